// Round 1
// baseline (502.705 us; speedup 1.0000x reference)
//
#include <hip/hip_runtime.h>
#include <hip/hip_bf16.h>

#define BB 32
#define NN 512
#define MM 512
#define DD 1024

typedef __attribute__((ext_vector_type(8))) short short8;
typedef __attribute__((ext_vector_type(4))) float f32x4;

__device__ inline unsigned short f2bf(float f) {
    unsigned int u = __float_as_uint(f);
    u += 0x7fffu + ((u >> 16) & 1u);
    return (unsigned short)(u >> 16);
}

// ---------------------------------------------------------------------------
// K0a: split x (fp32) -> hi (bf16 RNE) + lo (bf16 of exact residual)
// ---------------------------------------------------------------------------
__global__ __launch_bounds__(256) void convert_split(
    const float* __restrict__ x1, const float* __restrict__ x2,
    unsigned short* __restrict__ x1h, unsigned short* __restrict__ x1l,
    unsigned short* __restrict__ x2h, unsigned short* __restrict__ x2l) {
    size_t i = ((size_t)blockIdx.x * 256 + threadIdx.x) * 4;
    float4 a = *(const float4*)(x1 + i);
    float4 b = *(const float4*)(x2 + i);
    ushort4 ah, al, bh, bl;
#define SPLIT1(vv, hh, ll) { unsigned short h_ = f2bf(vv); \
    float hf_ = __uint_as_float((unsigned int)h_ << 16); \
    hh = h_; ll = f2bf((vv) - hf_); }
    SPLIT1(a.x, ah.x, al.x) SPLIT1(a.y, ah.y, al.y)
    SPLIT1(a.z, ah.z, al.z) SPLIT1(a.w, ah.w, al.w)
    SPLIT1(b.x, bh.x, bl.x) SPLIT1(b.y, bh.y, bl.y)
    SPLIT1(b.z, bh.z, bl.z) SPLIT1(b.w, bh.w, bl.w)
#undef SPLIT1
    *(ushort4*)(x1h + i) = ah;
    *(ushort4*)(x1l + i) = al;
    *(ushort4*)(x2h + i) = bh;
    *(ushort4*)(x2l + i) = bl;
}

// ---------------------------------------------------------------------------
// K0b: transpose bf16 [b][R=512][C=1024] -> [b][C][R], 64x64 LDS tiles
// ---------------------------------------------------------------------------
__global__ __launch_bounds__(256) void transpose_bf16(
    const unsigned short* __restrict__ src, unsigned short* __restrict__ dst) {
    const int R = 512, C = 1024;
    int bid = blockIdx.x;
    int b = bid >> 7; int rem = bid & 127;
    int r0 = (rem >> 4) * 64, c0 = (rem & 15) * 64;
    int t = threadIdx.x;
    __shared__ unsigned short lds[64 * 68];
    int j4 = (t & 15) * 4;
#pragma unroll
    for (int p = 0; p < 4; ++p) {
        int i = (t >> 4) + p * 16;
        *(ushort4*)&lds[i * 68 + j4] =
            *(const ushort4*)&src[((size_t)b * R + r0 + i) * C + c0 + j4];
    }
    __syncthreads();
#pragma unroll
    for (int p = 0; p < 4; ++p) {
        int i2 = (t >> 4) + p * 16;   // c-local
        ushort4 o;
        o.x = lds[(j4 + 0) * 68 + i2];
        o.y = lds[(j4 + 1) * 68 + i2];
        o.z = lds[(j4 + 2) * 68 + i2];
        o.w = lds[(j4 + 3) * 68 + i2];
        *(ushort4*)&dst[((size_t)b * C + c0 + i2) * R + r0 + j4] = o;
    }
}

// ---------------------------------------------------------------------------
// K1: align[b][n][m] = x1[b][n][:] . x2[b][m][:]  (split-bf16, 3-term MFMA)
// 128x128 tile / block, 4 waves, each wave 64x64 via 4x4 of 16x16x32 frags
// ---------------------------------------------------------------------------
__global__ __launch_bounds__(256) void gemm_align(
    const unsigned short* __restrict__ x1h, const unsigned short* __restrict__ x1l,
    const unsigned short* __restrict__ x2h, const unsigned short* __restrict__ x2l,
    float* __restrict__ alg) {
    __shared__ unsigned short Ah[128 * 40], Al[128 * 40], Bh[128 * 40], Bl[128 * 40];
    int bid = blockIdx.x;
    int b = bid >> 4; int tl = bid & 15;
    int n0 = (tl >> 2) * 128, m0 = (tl & 3) * 128;
    int t = threadIdx.x; int w = t >> 6; int l = t & 63;
    int lane16 = l & 15, q8 = (l >> 4) * 8;
    int wr = (w >> 1) * 64, wc = (w & 1) * 64;
    f32x4 acc[4][4];
#pragma unroll
    for (int i = 0; i < 4; ++i)
#pragma unroll
        for (int j = 0; j < 4; ++j) acc[i][j] = (f32x4){0.f, 0.f, 0.f, 0.f};
    const unsigned short* gAh = x1h + ((size_t)b * NN + n0) * DD;
    const unsigned short* gAl = x1l + ((size_t)b * NN + n0) * DD;
    const unsigned short* gBh = x2h + ((size_t)b * MM + m0) * DD;
    const unsigned short* gBl = x2l + ((size_t)b * MM + m0) * DD;
    int srow = t >> 2;            // 0..63 (c adds 64)
    int sdc = (t & 3) * 8;
    for (int kk = 0; kk < DD; kk += 32) {
        __syncthreads();
#pragma unroll
        for (int c = 0; c < 2; ++c) {
            int r2 = srow + c * 64;
            size_t go = (size_t)r2 * DD + kk + sdc;
            int lo = r2 * 40 + sdc;
            *(float4*)&Ah[lo] = *(const float4*)(gAh + go);
            *(float4*)&Al[lo] = *(const float4*)(gAl + go);
            *(float4*)&Bh[lo] = *(const float4*)(gBh + go);
            *(float4*)&Bl[lo] = *(const float4*)(gBl + go);
        }
        __syncthreads();
        short8 a_h[4], a_l[4], b_h[4], b_l[4];
#pragma unroll
        for (int i = 0; i < 4; ++i) {
            int r = (wr + i * 16 + lane16) * 40 + q8;
            a_h[i] = *(const short8*)&Ah[r];
            a_l[i] = *(const short8*)&Al[r];
        }
#pragma unroll
        for (int j = 0; j < 4; ++j) {
            int r = (wc + j * 16 + lane16) * 40 + q8;
            b_h[j] = *(const short8*)&Bh[r];
            b_l[j] = *(const short8*)&Bl[r];
        }
#pragma unroll
        for (int i = 0; i < 4; ++i)
#pragma unroll
            for (int j = 0; j < 4; ++j) {
                acc[i][j] = __builtin_amdgcn_mfma_f32_16x16x32_bf16(a_h[i], b_h[j], acc[i][j], 0, 0, 0);
                acc[i][j] = __builtin_amdgcn_mfma_f32_16x16x32_bf16(a_h[i], b_l[j], acc[i][j], 0, 0, 0);
                acc[i][j] = __builtin_amdgcn_mfma_f32_16x16x32_bf16(a_l[i], b_h[j], acc[i][j], 0, 0, 0);
            }
    }
    float* ob = alg + (size_t)b * NN * MM;
    int q4 = (l >> 4) * 4;
#pragma unroll
    for (int i = 0; i < 4; ++i)
#pragma unroll
        for (int j = 0; j < 4; ++j)
#pragma unroll
            for (int r = 0; r < 4; ++r) {
                int n = n0 + wr + i * 16 + q4 + r;
                int m = m0 + wc + j * 16 + lane16;
                ob[(size_t)n * MM + m] = acc[i][j][r];
            }
}

// ---------------------------------------------------------------------------
// K2: row softmax over m with mask2 -> attn12 bf16. One block per (b,n).
// ---------------------------------------------------------------------------
__global__ __launch_bounds__(256) void row_softmax(
    const float* __restrict__ alg, const int* __restrict__ mask2,
    unsigned short* __restrict__ attn12) {
    int row = blockIdx.x;          // b*NN + n
    int b = row >> 9;
    int t = threadIdx.x; int w = t >> 6; int l = t & 63;
    const float* ar = alg + (size_t)row * MM;
    int k0 = t, k1 = t + 256;
    int msk0 = mask2[b * MM + k0], msk1 = mask2[b * MM + k1];
    float v0 = ar[k0], v1 = ar[k1];
    float a0 = msk0 ? v0 : -3.0e38f, a1 = msk1 ? v1 : -3.0e38f;
    float mx = fmaxf(a0, a1);
#pragma unroll
    for (int o = 32; o; o >>= 1) mx = fmaxf(mx, __shfl_xor(mx, o));
    __shared__ float rmx[4], rsum[4];
    if (l == 0) rmx[w] = mx;
    __syncthreads();
    mx = fmaxf(fmaxf(rmx[0], rmx[1]), fmaxf(rmx[2], rmx[3]));
    float e0 = msk0 ? __expf(v0 - mx) : 0.0f;
    float e1 = msk1 ? __expf(v1 - mx) : 0.0f;
    float s = e0 + e1;
#pragma unroll
    for (int o = 32; o; o >>= 1) s += __shfl_xor(s, o);
    if (l == 0) rsum[w] = s;
    __syncthreads();
    s = rsum[0] + rsum[1] + rsum[2] + rsum[3];
    float inv = 1.0f / s;
    unsigned short* orow = attn12 + (size_t)row * MM;
    orow[k0] = f2bf(e0 * inv);
    orow[k1] = f2bf(e1 * inv);
}

// ---------------------------------------------------------------------------
// K3: column stats (max, 1/sum) over n with mask1. Block: 64 m-cols, 4 n-slices.
// ---------------------------------------------------------------------------
__global__ __launch_bounds__(256) void col_stats(
    const float* __restrict__ alg, const int* __restrict__ mask1,
    float* __restrict__ colmax, float* __restrict__ colinv) {
    int bid = blockIdx.x; int b = bid >> 3; int m0 = (bid & 7) * 64;
    int t = threadIdx.x; int s = t >> 6; int mj = t & 63;
    const float* base = alg + (size_t)b * NN * MM + m0 + mj;
    float mx = -3.0e38f, sum = 0.0f;
    for (int n = s * 128; n < s * 128 + 128; ++n) {
        if (mask1[b * NN + n]) {
            float v = base[(size_t)n * MM];
            if (v > mx) { sum *= __expf(mx - v); mx = v; }
            sum += __expf(v - mx);
        }
    }
    __shared__ float smx[4][64], ssm[4][64];
    smx[s][mj] = mx; ssm[s][mj] = sum;
    __syncthreads();
    if (t < 64) {
        float M1 = fmaxf(fmaxf(smx[0][t], smx[1][t]), fmaxf(smx[2][t], smx[3][t]));
        float S = 0.0f;
#pragma unroll
        for (int q = 0; q < 4; ++q) S += ssm[q][t] * __expf(smx[q][t] - M1);
        colmax[b * MM + m0 + t] = M1;
        colinv[b * MM + m0 + t] = 1.0f / S;
    }
}

// ---------------------------------------------------------------------------
// K4: attn21[b][m][n] = mask1[n] ? exp(align[n][m]-colmax[m])*colinv[m] : 0
//     (64x64 LDS transpose tiles, coalesced both sides)
// ---------------------------------------------------------------------------
__global__ __launch_bounds__(256) void col_softmax_t(
    const float* __restrict__ alg, const int* __restrict__ mask1,
    const float* __restrict__ colmax, const float* __restrict__ colinv,
    unsigned short* __restrict__ attn21) {
    int bid = blockIdx.x; int b = bid >> 6; int rem = bid & 63;
    int m0 = (rem >> 3) * 64, n0 = (rem & 7) * 64;
    int t = threadIdx.x;
    __shared__ float lds[64 * 65];
    int jj = t & 63; int ii = t >> 6;
#pragma unroll
    for (int p = 0; p < 16; ++p) {
        int i = ii + p * 4;
        lds[i * 65 + jj] = alg[((size_t)b * NN + n0 + i) * MM + m0 + jj];
    }
    __syncthreads();
#pragma unroll
    for (int p = 0; p < 16; ++p) {
        int mm = ii + p * 4;
        float cm = colmax[b * MM + m0 + mm];
        float ci = colinv[b * MM + m0 + mm];
        int nn = jj;
        int msk = mask1[b * NN + n0 + nn];
        float v = lds[nn * 65 + mm];
        unsigned short pv = msk ? f2bf(__expf(v - cm) * ci) : (unsigned short)0;
        attn21[((size_t)b * MM + m0 + mm) * NN + n0 + nn] = pv;
    }
}

// ---------------------------------------------------------------------------
// K5/K6: out[b][r][d] = sum_k P[b][r][k] * VT[b][d][k]   (plain bf16 MFMA)
// P: [b][512][512], VT: [b][1024][512], out: [b][512][1024]
// ---------------------------------------------------------------------------
__global__ __launch_bounds__(256) void gemm_pv(
    const unsigned short* __restrict__ P, const unsigned short* __restrict__ VT,
    float* __restrict__ out) {
    __shared__ unsigned short At[128 * 40], Bt[128 * 40];
    int bid = blockIdx.x;
    int b = bid >> 5; int rem = bid & 31;
    int n0 = (rem >> 3) * 128, d0 = (rem & 7) * 128;
    int t = threadIdx.x; int w = t >> 6; int l = t & 63;
    int lane16 = l & 15, q8 = (l >> 4) * 8;
    int wr = (w >> 1) * 64, wc = (w & 1) * 64;
    f32x4 acc[4][4];
#pragma unroll
    for (int i = 0; i < 4; ++i)
#pragma unroll
        for (int j = 0; j < 4; ++j) acc[i][j] = (f32x4){0.f, 0.f, 0.f, 0.f};
    const unsigned short* gA = P + ((size_t)b * 512 + n0) * 512;
    const unsigned short* gB = VT + ((size_t)b * DD + d0) * 512;
    int srow = t >> 2;
    int sdc = (t & 3) * 8;
    for (int kk = 0; kk < 512; kk += 32) {
        __syncthreads();
#pragma unroll
        for (int c = 0; c < 2; ++c) {
            int r2 = srow + c * 64;
            size_t go = (size_t)r2 * 512 + kk + sdc;
            int lo = r2 * 40 + sdc;
            *(float4*)&At[lo] = *(const float4*)(gA + go);
            *(float4*)&Bt[lo] = *(const float4*)(gB + go);
        }
        __syncthreads();
        short8 af[4], bf[4];
#pragma unroll
        for (int i = 0; i < 4; ++i)
            af[i] = *(const short8*)&At[(wr + i * 16 + lane16) * 40 + q8];
#pragma unroll
        for (int j = 0; j < 4; ++j)
            bf[j] = *(const short8*)&Bt[(wc + j * 16 + lane16) * 40 + q8];
#pragma unroll
        for (int i = 0; i < 4; ++i)
#pragma unroll
            for (int j = 0; j < 4; ++j)
                acc[i][j] = __builtin_amdgcn_mfma_f32_16x16x32_bf16(af[i], bf[j], acc[i][j], 0, 0, 0);
    }
    int q4 = (l >> 4) * 4;
#pragma unroll
    for (int i = 0; i < 4; ++i)
#pragma unroll
        for (int j = 0; j < 4; ++j)
#pragma unroll
            for (int r = 0; r < 4; ++r) {
                int rr = n0 + wr + i * 16 + q4 + r;
                int dd = d0 + wc + j * 16 + lane16;
                out[((size_t)b * 512 + rr) * DD + dd] = acc[i][j][r];
            }
}

// ---------------------------------------------------------------------------
// Workspace layout (224 MB):
//   x1h 0 | x2h 32M | x1hT 64M | x2hT 96M | x1l 128M | x2l 160M | align 192M
//   after gemm_align, x1l region is reused: attn12 @128M, colmax @144M,
//   colinv @144M+64K; x2l region reused: attn21 @160M.
// ---------------------------------------------------------------------------
extern "C" void kernel_launch(void* const* d_in, const int* in_sizes, int n_in,
                              void* d_out, int out_size, void* d_ws, size_t ws_size,
                              hipStream_t stream) {
    const float* x1 = (const float*)d_in[0];
    const float* x2 = (const float*)d_in[1];
    const int* mask1 = (const int*)d_in[2];
    const int* mask2 = (const int*)d_in[3];
    char* ws = (char*)d_ws;
    unsigned short* x1h  = (unsigned short*)(ws);
    unsigned short* x2h  = (unsigned short*)(ws + 33554432UL);
    unsigned short* x1hT = (unsigned short*)(ws + 67108864UL);
    unsigned short* x2hT = (unsigned short*)(ws + 100663296UL);
    unsigned short* x1l  = (unsigned short*)(ws + 134217728UL);
    unsigned short* x2l  = (unsigned short*)(ws + 167772160UL);
    float* alg           = (float*)(ws + 201326592UL);
    unsigned short* attn12 = (unsigned short*)(ws + 134217728UL);  // reuses x1l
    float* colmax        = (float*)(ws + 150994944UL);             // x1l + 16MB
    float* colinv        = (float*)(ws + 151060480UL);
    unsigned short* attn21 = (unsigned short*)(ws + 167772160UL);  // reuses x2l
    float* out1 = (float*)d_out;
    float* out2 = out1 + (size_t)BB * NN * DD;

    convert_split<<<16384, 256, 0, stream>>>(x1, x2, x1h, x1l, x2h, x2l);
    transpose_bf16<<<4096, 256, 0, stream>>>(x1h, x1hT);
    transpose_bf16<<<4096, 256, 0, stream>>>(x2h, x2hT);
    gemm_align<<<512, 256, 0, stream>>>(x1h, x1l, x2h, x2l, alg);
    row_softmax<<<16384, 256, 0, stream>>>(alg, mask2, attn12);
    col_stats<<<256, 256, 0, stream>>>(alg, mask1, colmax, colinv);
    col_softmax_t<<<2048, 256, 0, stream>>>(alg, mask1, colmax, colinv, attn21);
    gemm_pv<<<1024, 256, 0, stream>>>(attn12, x2hT, out1);
    gemm_pv<<<1024, 256, 0, stream>>>(attn21, x1hT, out2);
}

// Round 2
// 493.056 us; speedup vs baseline: 1.0196x; 1.0196x over previous
//
#include <hip/hip_runtime.h>
#include <hip/hip_bf16.h>

#define BB 32
#define NN 512
#define MM 512
#define DD 1024

typedef __attribute__((ext_vector_type(8))) short short8;
typedef __attribute__((ext_vector_type(4))) float f32x4;

#define ASYNC_COPY16(g, l) \
    __builtin_amdgcn_global_load_lds((__attribute__((address_space(1))) void*)(g), \
                                     (__attribute__((address_space(3))) void*)(l), 16, 0, 0)

__device__ inline unsigned short f2bf(float f) {
    unsigned int u = __float_as_uint(f);
    u += 0x7fffu + ((u >> 16) & 1u);
    return (unsigned short)(u >> 16);
}

#define SPLIT1(vv, hh, ll) { unsigned short h_ = f2bf(vv); \
    float hf_ = __uint_as_float((unsigned int)h_ << 16); \
    hh = h_; ll = f2bf((vv) - hf_); }

// ---------------------------------------------------------------------------
// K0: fused split-convert + transpose. Per 64x64 tile: read fp32, write
// hi (row-major), lo (row-major), hi^T. Grid 4096, each block does x1 & x2.
// ---------------------------------------------------------------------------
__device__ inline void conv_tile(const float* __restrict__ src,
                                 unsigned short* __restrict__ h,
                                 unsigned short* __restrict__ l,
                                 unsigned short* __restrict__ hT,
                                 unsigned short* lds, int b, int r0, int c0, int t) {
    int i = t >> 4, j4 = (t & 15) * 4;
#pragma unroll
    for (int p = 0; p < 4; ++p) {
        int rl = i + p * 16;
        size_t off = ((size_t)b * 512 + r0 + rl) * 1024 + c0 + j4;
        float4 v = *(const float4*)&src[off];
        ushort4 hh, ll;
        SPLIT1(v.x, hh.x, ll.x) SPLIT1(v.y, hh.y, ll.y)
        SPLIT1(v.z, hh.z, ll.z) SPLIT1(v.w, hh.w, ll.w)
        *(ushort4*)&h[off] = hh;
        *(ushort4*)&l[off] = ll;
        *(ushort4*)&lds[rl * 68 + j4] = hh;
    }
    __syncthreads();
#pragma unroll
    for (int p = 0; p < 4; ++p) {
        int cc = i + p * 16;
        ushort4 o;
        o.x = lds[(j4 + 0) * 68 + cc];
        o.y = lds[(j4 + 1) * 68 + cc];
        o.z = lds[(j4 + 2) * 68 + cc];
        o.w = lds[(j4 + 3) * 68 + cc];
        *(ushort4*)&hT[((size_t)b * 1024 + c0 + cc) * 512 + r0 + j4] = o;
    }
}

__global__ __launch_bounds__(256) void convert_split_t(
    const float* __restrict__ x1, const float* __restrict__ x2,
    unsigned short* __restrict__ x1h, unsigned short* __restrict__ x1l,
    unsigned short* __restrict__ x1hT,
    unsigned short* __restrict__ x2h, unsigned short* __restrict__ x2l,
    unsigned short* __restrict__ x2hT) {
    int bid = blockIdx.x;
    int b = bid >> 7; int rem = bid & 127;
    int r0 = (rem >> 4) * 64, c0 = (rem & 15) * 64;
    __shared__ unsigned short lds[64 * 68];
    int t = threadIdx.x;
    conv_tile(x1, x1h, x1l, x1hT, lds, b, r0, c0, t);
    __syncthreads();
    conv_tile(x2, x2h, x2l, x2hT, lds, b, r0, c0, t);
}

// ---------------------------------------------------------------------------
// K1: align = x1 . x2^T (split-bf16, 3-term). 128x128 tile, async LDS staging.
// Wave w stages array w (Ah/Al/Bh/Bl), 8x global_load_lds(16B) per k-step.
// ---------------------------------------------------------------------------
__global__ __launch_bounds__(256) void gemm_align(
    const unsigned short* __restrict__ x1h, const unsigned short* __restrict__ x1l,
    const unsigned short* __restrict__ x2h, const unsigned short* __restrict__ x2l,
    float* __restrict__ alg) {
    __shared__ unsigned short S[4][128 * 32];
    int bid = blockIdx.x;
    int nb = (bid & 7) * 64 + (bid >> 3);   // XCD batch-affinity swizzle
    int b = nb >> 4; int tl = nb & 15;
    int n0 = (tl >> 2) * 128, m0 = (tl & 3) * 128;
    int t = threadIdx.x; int w = t >> 6; int l = t & 63;
    int lane16 = l & 15, q8 = (l >> 4) * 8;
    int wr = (w >> 1) * 64, wc = (w & 1) * 64;
    f32x4 acc[4][4];
#pragma unroll
    for (int i = 0; i < 4; ++i)
#pragma unroll
        for (int j = 0; j < 4; ++j) acc[i][j] = (f32x4){0.f, 0.f, 0.f, 0.f};
    const unsigned short* gAh = x1h + ((size_t)b * NN + n0) * DD;
    const unsigned short* gAl = x1l + ((size_t)b * NN + n0) * DD;
    const unsigned short* gBh = x2h + ((size_t)b * MM + m0) * DD;
    const unsigned short* gBl = x2l + ((size_t)b * MM + m0) * DD;
    const unsigned short* gp;
    unsigned short* lp;
    if (w == 0)      { gp = gAh; lp = &S[0][0]; }
    else if (w == 1) { gp = gAl; lp = &S[1][0]; }
    else if (w == 2) { gp = gBh; lp = &S[2][0]; }
    else             { gp = gBl; lp = &S[3][0]; }
    const unsigned short* gbase = gp + (size_t)(l >> 2) * DD + (l & 3) * 8;
    for (int kk = 0; kk < DD; kk += 32) {
        __syncthreads();
#pragma unroll
        for (int p = 0; p < 8; ++p)
            ASYNC_COPY16(gbase + (size_t)(p * 16) * DD + kk, lp + p * 512);
        __syncthreads();
        short8 a_h[4], a_l[4], b_h[4], b_l[4];
#pragma unroll
        for (int i = 0; i < 4; ++i) {
            int r = (wr + i * 16 + lane16) * 32 + q8;
            a_h[i] = *(const short8*)&S[0][r];
            a_l[i] = *(const short8*)&S[1][r];
        }
#pragma unroll
        for (int j = 0; j < 4; ++j) {
            int r = (wc + j * 16 + lane16) * 32 + q8;
            b_h[j] = *(const short8*)&S[2][r];
            b_l[j] = *(const short8*)&S[3][r];
        }
#pragma unroll
        for (int i = 0; i < 4; ++i)
#pragma unroll
            for (int j = 0; j < 4; ++j) {
                acc[i][j] = __builtin_amdgcn_mfma_f32_16x16x32_bf16(a_h[i], b_h[j], acc[i][j], 0, 0, 0);
                acc[i][j] = __builtin_amdgcn_mfma_f32_16x16x32_bf16(a_h[i], b_l[j], acc[i][j], 0, 0, 0);
                acc[i][j] = __builtin_amdgcn_mfma_f32_16x16x32_bf16(a_l[i], b_h[j], acc[i][j], 0, 0, 0);
            }
    }
    float* ob = alg + (size_t)b * NN * MM;
    int q4 = (l >> 4) * 4;
#pragma unroll
    for (int i = 0; i < 4; ++i)
#pragma unroll
        for (int j = 0; j < 4; ++j)
#pragma unroll
            for (int r = 0; r < 4; ++r) {
                int n = n0 + wr + i * 16 + q4 + r;
                int m = m0 + wc + j * 16 + lane16;
                ob[(size_t)n * MM + m] = acc[i][j][r];
            }
}

// ---------------------------------------------------------------------------
// K2: row softmax over m with mask2 -> attn12 bf16. One block per (b,n).
// ---------------------------------------------------------------------------
__global__ __launch_bounds__(256) void row_softmax(
    const float* __restrict__ alg, const int* __restrict__ mask2,
    unsigned short* __restrict__ attn12) {
    int row = blockIdx.x;
    int b = row >> 9;
    int t = threadIdx.x; int w = t >> 6; int l = t & 63;
    const float* ar = alg + (size_t)row * MM;
    int k0 = t, k1 = t + 256;
    int msk0 = mask2[b * MM + k0], msk1 = mask2[b * MM + k1];
    float v0 = ar[k0], v1 = ar[k1];
    float a0 = msk0 ? v0 : -3.0e38f, a1 = msk1 ? v1 : -3.0e38f;
    float mx = fmaxf(a0, a1);
#pragma unroll
    for (int o = 32; o; o >>= 1) mx = fmaxf(mx, __shfl_xor(mx, o));
    __shared__ float rmx[4], rsum[4];
    if (l == 0) rmx[w] = mx;
    __syncthreads();
    mx = fmaxf(fmaxf(rmx[0], rmx[1]), fmaxf(rmx[2], rmx[3]));
    float e0 = msk0 ? __expf(v0 - mx) : 0.0f;
    float e1 = msk1 ? __expf(v1 - mx) : 0.0f;
    float s = e0 + e1;
#pragma unroll
    for (int o = 32; o; o >>= 1) s += __shfl_xor(s, o);
    if (l == 0) rsum[w] = s;
    __syncthreads();
    s = rsum[0] + rsum[1] + rsum[2] + rsum[3];
    float inv = 1.0f / s;
    unsigned short* orow = attn12 + (size_t)row * MM;
    orow[k0] = f2bf(e0 * inv);
    orow[k1] = f2bf(e1 * inv);
}

// ---------------------------------------------------------------------------
// K3: column stats (max, 1/sum) over n with mask1.
// ---------------------------------------------------------------------------
__global__ __launch_bounds__(256) void col_stats(
    const float* __restrict__ alg, const int* __restrict__ mask1,
    float* __restrict__ colmax, float* __restrict__ colinv) {
    int bid = blockIdx.x; int b = bid >> 3; int m0 = (bid & 7) * 64;
    int t = threadIdx.x; int s = t >> 6; int mj = t & 63;
    const float* base = alg + (size_t)b * NN * MM + m0 + mj;
    float mx = -3.0e38f, sum = 0.0f;
    for (int n = s * 128; n < s * 128 + 128; ++n) {
        if (mask1[b * NN + n]) {
            float v = base[(size_t)n * MM];
            if (v > mx) { sum *= __expf(mx - v); mx = v; }
            sum += __expf(v - mx);
        }
    }
    __shared__ float smx[4][64], ssm[4][64];
    smx[s][mj] = mx; ssm[s][mj] = sum;
    __syncthreads();
    if (t < 64) {
        float M1 = fmaxf(fmaxf(smx[0][t], smx[1][t]), fmaxf(smx[2][t], smx[3][t]));
        float S = 0.0f;
#pragma unroll
        for (int q = 0; q < 4; ++q) S += ssm[q][t] * __expf(smx[q][t] - M1);
        colmax[b * MM + m0 + t] = M1;
        colinv[b * MM + m0 + t] = 1.0f / S;
    }
}

// ---------------------------------------------------------------------------
// K4: attn21[b][m][n] = mask1[n] ? exp(align[n][m]-colmax[m])*colinv[m] : 0
// ---------------------------------------------------------------------------
__global__ __launch_bounds__(256) void col_softmax_t(
    const float* __restrict__ alg, const int* __restrict__ mask1,
    const float* __restrict__ colmax, const float* __restrict__ colinv,
    unsigned short* __restrict__ attn21) {
    int bid = blockIdx.x; int b = bid >> 6; int rem = bid & 63;
    int m0 = (rem >> 3) * 64, n0 = (rem & 7) * 64;
    int t = threadIdx.x;
    __shared__ float lds[64 * 65];
    int jj = t & 63; int ii = t >> 6;
#pragma unroll
    for (int p = 0; p < 16; ++p) {
        int i = ii + p * 4;
        lds[i * 65 + jj] = alg[((size_t)b * NN + n0 + i) * MM + m0 + jj];
    }
    __syncthreads();
#pragma unroll
    for (int p = 0; p < 16; ++p) {
        int mm = ii + p * 4;
        float cm = colmax[b * MM + m0 + mm];
        float ci = colinv[b * MM + m0 + mm];
        int nn = jj;
        int msk = mask1[b * NN + n0 + nn];
        float v = lds[nn * 65 + mm];
        unsigned short pv = msk ? f2bf(__expf(v - cm) * ci) : (unsigned short)0;
        attn21[((size_t)b * MM + m0 + mm) * NN + n0 + nn] = pv;
    }
}

// ---------------------------------------------------------------------------
// K5/K6: out[b][r][d] = sum_k P[b][r][k] * VT[b][d][k]  (bf16 MFMA, async)
// ---------------------------------------------------------------------------
__global__ __launch_bounds__(256) void gemm_pv(
    const unsigned short* __restrict__ P, const unsigned short* __restrict__ VT,
    float* __restrict__ out) {
    __shared__ unsigned short S[2][128 * 32];
    int bid = blockIdx.x;
    int nb = (bid & 7) * 128 + (bid >> 3);  // XCD batch-affinity swizzle
    int b = nb >> 5; int rem = nb & 31;
    int n0 = (rem >> 3) * 128, d0 = (rem & 7) * 128;
    int t = threadIdx.x; int w = t >> 6; int l = t & 63;
    int lane16 = l & 15, q8 = (l >> 4) * 8;
    int wr = (w >> 1) * 64, wc = (w & 1) * 64;
    f32x4 acc[4][4];
#pragma unroll
    for (int i = 0; i < 4; ++i)
#pragma unroll
        for (int j = 0; j < 4; ++j) acc[i][j] = (f32x4){0.f, 0.f, 0.f, 0.f};
    const unsigned short* gA = P + ((size_t)b * 512 + n0) * 512;
    const unsigned short* gB = VT + ((size_t)b * DD + d0) * 512;
    int w2 = w & 1;
    const unsigned short* gp = (w < 2) ? gA : gB;
    unsigned short* lp = (w < 2) ? &S[0][0] : &S[1][0];
    const unsigned short* gbase = gp + (size_t)(w2 * 64 + (l >> 2)) * 512 + (l & 3) * 8;
    unsigned short* lbase = lp + w2 * 2048;
    for (int kk = 0; kk < 512; kk += 32) {
        __syncthreads();
#pragma unroll
        for (int p = 0; p < 4; ++p)
            ASYNC_COPY16(gbase + (size_t)(p * 16) * 512 + kk, lbase + p * 512);
        __syncthreads();
        short8 af[4], bf[4];
#pragma unroll
        for (int i = 0; i < 4; ++i)
            af[i] = *(const short8*)&S[0][(wr + i * 16 + lane16) * 32 + q8];
#pragma unroll
        for (int j = 0; j < 4; ++j)
            bf[j] = *(const short8*)&S[1][(wc + j * 16 + lane16) * 32 + q8];
#pragma unroll
        for (int i = 0; i < 4; ++i)
#pragma unroll
            for (int j = 0; j < 4; ++j)
                acc[i][j] = __builtin_amdgcn_mfma_f32_16x16x32_bf16(af[i], bf[j], acc[i][j], 0, 0, 0);
    }
    int q4 = (l >> 4) * 4;
#pragma unroll
    for (int i = 0; i < 4; ++i)
#pragma unroll
        for (int j = 0; j < 4; ++j)
#pragma unroll
            for (int r = 0; r < 4; ++r) {
                int rr = n0 + wr + i * 16 + q4 + r;
                int dd = d0 + wc + j * 16 + lane16;
                out[((size_t)b * 512 + rr) * DD + dd] = acc[i][j][r];
            }
}

// ---------------------------------------------------------------------------
extern "C" void kernel_launch(void* const* d_in, const int* in_sizes, int n_in,
                              void* d_out, int out_size, void* d_ws, size_t ws_size,
                              hipStream_t stream) {
    const float* x1 = (const float*)d_in[0];
    const float* x2 = (const float*)d_in[1];
    const int* mask1 = (const int*)d_in[2];
    const int* mask2 = (const int*)d_in[3];
    char* ws = (char*)d_ws;
    unsigned short* x1h  = (unsigned short*)(ws);
    unsigned short* x2h  = (unsigned short*)(ws + 33554432UL);
    unsigned short* x1hT = (unsigned short*)(ws + 67108864UL);
    unsigned short* x2hT = (unsigned short*)(ws + 100663296UL);
    unsigned short* x1l  = (unsigned short*)(ws + 134217728UL);
    unsigned short* x2l  = (unsigned short*)(ws + 167772160UL);
    float* alg           = (float*)(ws + 201326592UL);
    unsigned short* attn12 = (unsigned short*)(ws + 134217728UL);  // reuses x1l
    float* colmax        = (float*)(ws + 150994944UL);
    float* colinv        = (float*)(ws + 151060480UL);
    unsigned short* attn21 = (unsigned short*)(ws + 167772160UL);  // reuses x2l
    float* out1 = (float*)d_out;
    float* out2 = out1 + (size_t)BB * NN * DD;

    convert_split_t<<<4096, 256, 0, stream>>>(x1, x2, x1h, x1l, x1hT, x2h, x2l, x2hT);
    gemm_align<<<512, 256, 0, stream>>>(x1h, x1l, x2h, x2l, alg);
    row_softmax<<<16384, 256, 0, stream>>>(alg, mask2, attn12);
    col_stats<<<256, 256, 0, stream>>>(alg, mask1, colmax, colinv);
    col_softmax_t<<<2048, 256, 0, stream>>>(alg, mask1, colmax, colinv, attn21);
    gemm_pv<<<1024, 256, 0, stream>>>(attn12, x2hT, out1);
    gemm_pv<<<1024, 256, 0, stream>>>(attn21, x1hT, out2);
}

// Round 3
// 459.283 us; speedup vs baseline: 1.0945x; 1.0735x over previous
//
#include <hip/hip_runtime.h>
#include <hip/hip_bf16.h>

#define BB 32
#define NN 512
#define MM 512
#define DD 1024

typedef __attribute__((ext_vector_type(8))) short short8;
typedef __attribute__((ext_vector_type(4))) float f32x4;

#define ASYNC_COPY16(g, l) \
    __builtin_amdgcn_global_load_lds((__attribute__((address_space(1))) void*)(g), \
                                     (__attribute__((address_space(3))) void*)(l), 16, 0, 0)

__device__ inline unsigned short f2bf(float f) {
    unsigned int u = __float_as_uint(f);
    u += 0x7fffu + ((u >> 16) & 1u);
    return (unsigned short)(u >> 16);
}

#define SPLIT1(vv, hh, ll) { unsigned short h_ = f2bf(vv); \
    float hf_ = __uint_as_float((unsigned int)h_ << 16); \
    hh = h_; ll = f2bf((vv) - hf_); }

// ---------------------------------------------------------------------------
// K0: fused split-convert + transpose. 256(r) x 64(c) tiles.
// Reads fp32 (256B segs), writes h/l row-major (128B segs) and hT with
// 512B/wave contiguous column writes.
// ---------------------------------------------------------------------------
__device__ inline void conv_tile2(const float* __restrict__ src,
                                  unsigned short* __restrict__ h,
                                  unsigned short* __restrict__ l,
                                  unsigned short* __restrict__ hT,
                                  unsigned short* lds, int b, int r0, int c0, int t) {
    int i = t >> 4, j4 = (t & 15) * 4;
#pragma unroll
    for (int p = 0; p < 16; ++p) {
        int r = i + p * 16;
        size_t off = ((size_t)b * 512 + r0 + r) * 1024 + c0 + j4;
        float4 v = *(const float4*)&src[off];
        ushort4 hh, ll;
        SPLIT1(v.x, hh.x, ll.x) SPLIT1(v.y, hh.y, ll.y)
        SPLIT1(v.z, hh.z, ll.z) SPLIT1(v.w, hh.w, ll.w)
        *(ushort4*)&h[off] = hh;
        *(ushort4*)&l[off] = ll;
        *(ushort4*)&lds[r * 68 + j4] = hh;
    }
    __syncthreads();
    int c4 = t >> 6;            // 0..3
    int rr = (t & 63) * 4;      // 0..252
#pragma unroll
    for (int p = 0; p < 16; ++p) {
        int c = c4 + p * 4;     // 0..63
        ushort4 o;
        o.x = lds[(rr + 0) * 68 + c];
        o.y = lds[(rr + 1) * 68 + c];
        o.z = lds[(rr + 2) * 68 + c];
        o.w = lds[(rr + 3) * 68 + c];
        *(ushort4*)&hT[((size_t)b * 1024 + c0 + c) * 512 + r0 + rr] = o;
    }
}

__global__ __launch_bounds__(256) void convert_split_t(
    const float* __restrict__ x1, const float* __restrict__ x2,
    unsigned short* __restrict__ x1h, unsigned short* __restrict__ x1l,
    unsigned short* __restrict__ x1hT,
    unsigned short* __restrict__ x2h, unsigned short* __restrict__ x2l,
    unsigned short* __restrict__ x2hT) {
    int bid = blockIdx.x;
    int b = bid >> 5; int rem = bid & 31;
    int r0 = (rem >> 4) * 256, c0 = (rem & 15) * 64;
    __shared__ unsigned short lds[256 * 68];
    int t = threadIdx.x;
    conv_tile2(x1, x1h, x1l, x1hT, lds, b, r0, c0, t);
    __syncthreads();
    conv_tile2(x2, x2h, x2l, x2hT, lds, b, r0, c0, t);
}

// ---------------------------------------------------------------------------
// K1: align = x1 . x2^T (split-bf16, 3-term) + fused tile-local softmax
// partial stats. 64(n) x 128(m) tiles, grid 1024 (4 blocks/CU).
// Each wave: 64n x 32m (4x2 frags of 16x16x32).
// ---------------------------------------------------------------------------
__global__ __launch_bounds__(256) void gemm_align(
    const unsigned short* __restrict__ x1h, const unsigned short* __restrict__ x1l,
    const unsigned short* __restrict__ x2h, const unsigned short* __restrict__ x2l,
    const int* __restrict__ mask1, const int* __restrict__ mask2,
    float* __restrict__ alg,
    float* __restrict__ rp_max, float* __restrict__ rp_sum,
    float* __restrict__ cp_max, float* __restrict__ cp_sum) {
    // SA_h 2048 | SA_l 2048 | SB_h 4096 | SB_l 4096  (elems) = 24KB
    __shared__ unsigned short S[12288];
    int bid = blockIdx.x;
    int nb = (bid & 7) * 128 + (bid >> 3);   // XCD batch-affinity swizzle
    int b = nb >> 5; int tl = nb & 31;
    int nt = tl >> 2, mt = tl & 3;
    int n0 = nt * 64, m0 = mt * 128;
    int t = threadIdx.x; int w = t >> 6; int l = t & 63;
    int lane16 = l & 15, q = l >> 4, q8 = q * 8;
    int wc = w * 32;
    f32x4 acc[4][2];
#pragma unroll
    for (int i = 0; i < 4; ++i)
#pragma unroll
        for (int j = 0; j < 2; ++j) acc[i][j] = (f32x4){0.f, 0.f, 0.f, 0.f};
    // async staging: 24 x 1KB wave-instructions, 6 per wave
    const unsigned short* gs[6];
    int ls[6];
#pragma unroll
    for (int s = 0; s < 6; ++s) {
        int qq = w * 6 + s;
        const unsigned short* base; int lb; int row0;
        if (qq < 4)       { base = x1h + ((size_t)b * 512 + n0) * 1024; lb = 0;    row0 = qq * 16; }
        else if (qq < 8)  { base = x1l + ((size_t)b * 512 + n0) * 1024; lb = 2048; row0 = (qq - 4) * 16; }
        else if (qq < 16) { base = x2h + ((size_t)b * 512 + m0) * 1024; lb = 4096; row0 = (qq - 8) * 16; }
        else              { base = x2l + ((size_t)b * 512 + m0) * 1024; lb = 8192; row0 = (qq - 16) * 16; }
        gs[s] = base + (size_t)(row0 + (l >> 2)) * 1024 + (l & 3) * 8;
        ls[s] = lb + row0 * 32 + l * 8;
    }
    for (int kk = 0; kk < 1024; kk += 32) {
        __syncthreads();
#pragma unroll
        for (int s = 0; s < 6; ++s)
            ASYNC_COPY16(gs[s] + kk, &S[ls[s]]);
        __syncthreads();
        short8 ah[4], al[4], bh[2], bl[2];
#pragma unroll
        for (int i = 0; i < 4; ++i) {
            int off = (i * 16 + lane16) * 32 + q8;
            ah[i] = *(const short8*)&S[off];
            al[i] = *(const short8*)&S[2048 + off];
        }
#pragma unroll
        for (int j = 0; j < 2; ++j) {
            int off = (wc + j * 16 + lane16) * 32 + q8;
            bh[j] = *(const short8*)&S[4096 + off];
            bl[j] = *(const short8*)&S[8192 + off];
        }
#pragma unroll
        for (int i = 0; i < 4; ++i)
#pragma unroll
            for (int j = 0; j < 2; ++j) {
                acc[i][j] = __builtin_amdgcn_mfma_f32_16x16x32_bf16(ah[i], bh[j], acc[i][j], 0, 0, 0);
                acc[i][j] = __builtin_amdgcn_mfma_f32_16x16x32_bf16(ah[i], bl[j], acc[i][j], 0, 0, 0);
                acc[i][j] = __builtin_amdgcn_mfma_f32_16x16x32_bf16(al[i], bh[j], acc[i][j], 0, 0, 0);
            }
    }
    // ---- C store ----
    float* ob = alg + ((size_t)b * 512 + n0) * 512 + m0;
    int q4 = q * 4;
#pragma unroll
    for (int i = 0; i < 4; ++i)
#pragma unroll
        for (int j = 0; j < 2; ++j)
#pragma unroll
            for (int r = 0; r < 4; ++r)
                ob[(size_t)(i * 16 + q4 + r) * 512 + wc + j * 16 + lane16] = acc[i][j][r];
    // ---- masks ----
    int mk2[2];
#pragma unroll
    for (int j = 0; j < 2; ++j) mk2[j] = mask2[b * 512 + m0 + wc + j * 16 + lane16];
    int mk1r[4][4];
#pragma unroll
    for (int i = 0; i < 4; ++i)
#pragma unroll
        for (int r = 0; r < 4; ++r) mk1r[i][r] = mask1[b * 512 + n0 + i * 16 + q4 + r];
    // ---- col partials (over the tile's 64 n, per m-col) ----
#pragma unroll
    for (int j = 0; j < 2; ++j) {
        float cm = -3.0e38f;
#pragma unroll
        for (int i = 0; i < 4; ++i)
#pragma unroll
            for (int r = 0; r < 4; ++r)
                if (mk1r[i][r]) cm = fmaxf(cm, acc[i][j][r]);
        cm = fmaxf(cm, __shfl_xor(cm, 16));
        cm = fmaxf(cm, __shfl_xor(cm, 32));
        float cs = 0.f;
#pragma unroll
        for (int i = 0; i < 4; ++i)
#pragma unroll
            for (int r = 0; r < 4; ++r)
                cs += mk1r[i][r] ? __expf(acc[i][j][r] - cm) : 0.f;
        cs += __shfl_xor(cs, 16);
        cs += __shfl_xor(cs, 32);
        if (q == 0) {
            size_t o = ((size_t)b * 8 + nt) * 512 + m0 + wc + j * 16 + lane16;
            cp_max[o] = cm;
            cp_sum[o] = cs;
        }
    }
    // ---- row partials (over this wave's 32 m, per n-row), combine 4 waves in LDS ----
    __syncthreads();               // S reuse safe: all waves done reading frags
    float* rmS = (float*)S;        // [4][64]
    float* rsS = rmS + 256;        // [4][64]
#pragma unroll
    for (int i = 0; i < 4; ++i)
#pragma unroll
        for (int r = 0; r < 4; ++r) {
            float v0 = acc[i][0][r], v1 = acc[i][1][r];
            float rm = fmaxf(mk2[0] ? v0 : -3.0e38f, mk2[1] ? v1 : -3.0e38f);
            rm = fmaxf(rm, __shfl_xor(rm, 1));
            rm = fmaxf(rm, __shfl_xor(rm, 2));
            rm = fmaxf(rm, __shfl_xor(rm, 4));
            rm = fmaxf(rm, __shfl_xor(rm, 8));
            float rs = (mk2[0] ? __expf(v0 - rm) : 0.f) + (mk2[1] ? __expf(v1 - rm) : 0.f);
            rs += __shfl_xor(rs, 1);
            rs += __shfl_xor(rs, 2);
            rs += __shfl_xor(rs, 4);
            rs += __shfl_xor(rs, 8);
            if (lane16 == 0) {
                int row = i * 16 + q4 + r;
                rmS[w * 64 + row] = rm;
                rsS[w * 64 + row] = rs;
            }
        }
    __syncthreads();
    if (t < 64) {
        float M = -3.0e38f;
#pragma unroll
        for (int ww = 0; ww < 4; ++ww) M = fmaxf(M, rmS[ww * 64 + t]);
        float Ssum = 0.f;
#pragma unroll
        for (int ww = 0; ww < 4; ++ww) Ssum += rsS[ww * 64 + t] * __expf(rmS[ww * 64 + t] - M);
        size_t o = ((size_t)b * 4 + mt) * 512 + n0 + t;
        rp_max[o] = M;
        rp_sum[o] = Ssum;
    }
}

// ---------------------------------------------------------------------------
// K2: combine partials -> rowmax/rowinv (per b,n) and colmax/colinv (per b,m)
// ---------------------------------------------------------------------------
__global__ __launch_bounds__(256) void combine_stats(
    const float* __restrict__ rp_max, const float* __restrict__ rp_sum,
    const float* __restrict__ cp_max, const float* __restrict__ cp_sum,
    float* __restrict__ rowmax, float* __restrict__ rowinv,
    float* __restrict__ colmax, float* __restrict__ colinv) {
    int idx = blockIdx.x * 256 + threadIdx.x;   // 0..32767
    if (idx < 16384) {
        int b = idx >> 9, n = idx & 511;
        float M = -3.0e38f;
#pragma unroll
        for (int tt = 0; tt < 4; ++tt) M = fmaxf(M, rp_max[((size_t)b * 4 + tt) * 512 + n]);
        float S = 0.f;
#pragma unroll
        for (int tt = 0; tt < 4; ++tt) {
            size_t o = ((size_t)b * 4 + tt) * 512 + n;
            S += rp_sum[o] * __expf(rp_max[o] - M);
        }
        rowmax[idx] = M;
        rowinv[idx] = 1.0f / S;
    } else {
        int id2 = idx - 16384;
        int b = id2 >> 9, m = id2 & 511;
        float M = -3.0e38f;
#pragma unroll
        for (int tt = 0; tt < 8; ++tt) M = fmaxf(M, cp_max[((size_t)b * 8 + tt) * 512 + m]);
        float S = 0.f;
#pragma unroll
        for (int tt = 0; tt < 8; ++tt) {
            size_t o = ((size_t)b * 8 + tt) * 512 + m;
            S += cp_sum[o] * __expf(cp_max[o] - M);
        }
        colmax[id2] = M;
        colinv[id2] = 1.0f / S;
    }
}

// ---------------------------------------------------------------------------
// K3: apply — read align once, write attn12[n][m] and attn21[m][n] (bf16)
// ---------------------------------------------------------------------------
__global__ __launch_bounds__(256) void apply_softmax(
    const float* __restrict__ alg, const int* __restrict__ mask1,
    const int* __restrict__ mask2,
    const float* __restrict__ rowmax, const float* __restrict__ rowinv,
    const float* __restrict__ colmax, const float* __restrict__ colinv,
    unsigned short* __restrict__ attn12, unsigned short* __restrict__ attn21) {
    int bid = blockIdx.x; int b = bid >> 6; int rem = bid & 63;
    int m0 = (rem >> 3) * 64, n0 = (rem & 7) * 64;
    int t = threadIdx.x;
    __shared__ float lds[64 * 65];
    int jj = t & 63; int ii = t >> 6;
    int mk2 = mask2[b * 512 + m0 + jj];
#pragma unroll
    for (int p = 0; p < 16; ++p) {
        int n = ii + p * 4;
        float v = alg[((size_t)b * 512 + n0 + n) * 512 + m0 + jj];
        lds[n * 65 + jj] = v;
        float rm = rowmax[b * 512 + n0 + n];
        float ri = rowinv[b * 512 + n0 + n];
        float e = mk2 ? __expf(v - rm) * ri : 0.f;
        attn12[((size_t)b * 512 + n0 + n) * 512 + m0 + jj] = f2bf(e);
    }
    __syncthreads();
    int mk1 = mask1[b * 512 + n0 + jj];
#pragma unroll
    for (int p = 0; p < 16; ++p) {
        int mm = ii + p * 4;
        float cm = colmax[b * 512 + m0 + mm];
        float ci = colinv[b * 512 + m0 + mm];
        float v = lds[jj * 65 + mm];
        unsigned short pv = mk1 ? f2bf(__expf(v - cm) * ci) : (unsigned short)0;
        attn21[((size_t)b * 512 + m0 + mm) * 512 + n0 + jj] = pv;
    }
}

// ---------------------------------------------------------------------------
// K4/K5: out[b][r][d] = sum_k P[b][r][k] * VT[b][d][k]  (bf16 MFMA, async)
// ---------------------------------------------------------------------------
__global__ __launch_bounds__(256) void gemm_pv(
    const unsigned short* __restrict__ P, const unsigned short* __restrict__ VT,
    float* __restrict__ out) {
    __shared__ unsigned short S[2][128 * 32];
    int bid = blockIdx.x;
    int nb = (bid & 7) * 128 + (bid >> 3);  // XCD batch-affinity swizzle
    int b = nb >> 5; int rem = nb & 31;
    int n0 = (rem >> 3) * 128, d0 = (rem & 7) * 128;
    int t = threadIdx.x; int w = t >> 6; int l = t & 63;
    int lane16 = l & 15, q8 = (l >> 4) * 8;
    int wr = (w >> 1) * 64, wc = (w & 1) * 64;
    f32x4 acc[4][4];
#pragma unroll
    for (int i = 0; i < 4; ++i)
#pragma unroll
        for (int j = 0; j < 4; ++j) acc[i][j] = (f32x4){0.f, 0.f, 0.f, 0.f};
    const unsigned short* gA = P + ((size_t)b * 512 + n0) * 512;
    const unsigned short* gB = VT + ((size_t)b * DD + d0) * 512;
    int w2 = w & 1;
    const unsigned short* gp = (w < 2) ? gA : gB;
    unsigned short* lp = (w < 2) ? &S[0][0] : &S[1][0];
    const unsigned short* gbase = gp + (size_t)(w2 * 64 + (l >> 2)) * 512 + (l & 3) * 8;
    unsigned short* lbase = lp + w2 * 2048;
    for (int kk = 0; kk < 512; kk += 32) {
        __syncthreads();
#pragma unroll
        for (int p = 0; p < 4; ++p)
            ASYNC_COPY16(gbase + (size_t)(p * 16) * 512 + kk, lbase + p * 512);
        __syncthreads();
        short8 af[4], bf[4];
#pragma unroll
        for (int i = 0; i < 4; ++i)
            af[i] = *(const short8*)&S[0][(wr + i * 16 + lane16) * 32 + q8];
#pragma unroll
        for (int j = 0; j < 4; ++j)
            bf[j] = *(const short8*)&S[1][(wc + j * 16 + lane16) * 32 + q8];
#pragma unroll
        for (int i = 0; i < 4; ++i)
#pragma unroll
            for (int j = 0; j < 4; ++j)
                acc[i][j] = __builtin_amdgcn_mfma_f32_16x16x32_bf16(af[i], bf[j], acc[i][j], 0, 0, 0);
    }
    int q4 = (l >> 4) * 4;
#pragma unroll
    for (int i = 0; i < 4; ++i)
#pragma unroll
        for (int j = 0; j < 4; ++j)
#pragma unroll
            for (int r = 0; r < 4; ++r) {
                int rr = n0 + wr + i * 16 + q4 + r;
                int dd = d0 + wc + j * 16 + lane16;
                out[((size_t)b * 512 + rr) * DD + dd] = acc[i][j][r];
            }
}

// ---------------------------------------------------------------------------
// ws layout (224MB): x1h 0 | x2h 32M | x1hT 64M | x2hT 96M | x1l 128M |
//   x2l 160M | alg 192M.  After gemm_align: attn12 @128M (16MB), stats
//   @144M (256KB), attn21 @160M (16MB).  Partials live in d_out scratch
//   (overwritten by gemm_pv afterwards).
// ---------------------------------------------------------------------------
extern "C" void kernel_launch(void* const* d_in, const int* in_sizes, int n_in,
                              void* d_out, int out_size, void* d_ws, size_t ws_size,
                              hipStream_t stream) {
    const float* x1 = (const float*)d_in[0];
    const float* x2 = (const float*)d_in[1];
    const int* mask1 = (const int*)d_in[2];
    const int* mask2 = (const int*)d_in[3];
    char* ws = (char*)d_ws;
    unsigned short* x1h  = (unsigned short*)(ws);
    unsigned short* x2h  = (unsigned short*)(ws + 33554432UL);
    unsigned short* x1hT = (unsigned short*)(ws + 67108864UL);
    unsigned short* x2hT = (unsigned short*)(ws + 100663296UL);
    unsigned short* x1l  = (unsigned short*)(ws + 134217728UL);
    unsigned short* x2l  = (unsigned short*)(ws + 167772160UL);
    float* alg           = (float*)(ws + 201326592UL);
    unsigned short* attn12 = (unsigned short*)(ws + 134217728UL);  // reuses x1l
    float* rowmax        = (float*)(ws + 150994944UL);             // @144MB
    float* rowinv        = (float*)(ws + 151060480UL);
    float* colmax        = (float*)(ws + 151126016UL);
    float* colinv        = (float*)(ws + 151191552UL);
    unsigned short* attn21 = (unsigned short*)(ws + 167772160UL);  // reuses x2l
    float* out1 = (float*)d_out;
    float* out2 = out1 + (size_t)BB * NN * DD;
    // partial stats scratch in d_out (dead before gemm_pv writes it)
    float* rp_max = (float*)d_out;            // [32][4][512]
    float* rp_sum = rp_max + 65536;
    float* cp_max = rp_sum + 65536;           // [32][8][512]
    float* cp_sum = cp_max + 131072;

    convert_split_t<<<1024, 256, 0, stream>>>(x1, x2, x1h, x1l, x1hT, x2h, x2l, x2hT);
    gemm_align<<<1024, 256, 0, stream>>>(x1h, x1l, x2h, x2l, mask1, mask2, alg,
                                         rp_max, rp_sum, cp_max, cp_sum);
    combine_stats<<<128, 256, 0, stream>>>(rp_max, rp_sum, cp_max, cp_sum,
                                           rowmax, rowinv, colmax, colinv);
    apply_softmax<<<2048, 256, 0, stream>>>(alg, mask1, mask2, rowmax, rowinv,
                                            colmax, colinv, attn12, attn21);
    gemm_pv<<<1024, 256, 0, stream>>>(attn12, x2hT, out1);
    gemm_pv<<<1024, 256, 0, stream>>>(attn21, x1hT, out2);
}